// Round 5
// baseline (320.268 us; speedup 1.0000x reference)
//
#include <hip/hip_runtime.h>

// GCNEncoder: 2-layer GCN (sym-norm, self-loops) + LayerNorm. N=100000, E=1600000, D=128.
// Round 15. r14 post-mortem: bucket-split+repack gained only 4.8us (pred 25) -> prep
// lump (~159us incl gemm2+gaps) still unattributed; gathers pinned at floor (75.4us,
// 3.35TB/s, FETCH 196MB). This round: barrier-free fusion of gemm2 into gather_relu.
// r12's failure was the CROSS-WAVE barrier (max of 16 Poisson degrees); here one
// 64-thread block = one wave = 16 nodes gathered SERIALLY (inner edge loop byte-
// identical to r10), rows parked in wave-private LDS (stride 68 u32: 16B-aligned,
// write conflict-free), then the wave alone runs 8 ntile x 4 kb MFMAs with B-frags
// streamed from prebuilt w2frag (L2-resident). No __syncthreads anywhere. Per-wave
// work = SUM of 16 degrees (+-6%), tighter than r10's per-node max. Kills the
// gemm_bf16in dispatch + X2 round-trip + one gap. Self-instruments: fused kernel
// should land ~76-85us -> visible in top-5 next round.

#define N_NODES 100000
#define N_EDGES 1600000
#define NBLK_N  391          // ceil(N_NODES/256)
#define NB      391          // buckets = ceil(N/256), 256-node buckets
#define BKT_CAP 4736         // mean 4092 + ~10 sigma, overflow-guarded
#define BIN_GRID 391         // binning blocks, 4096 edges each
#define GEMM_GRID 1563       // ceil(N/64)
#define MM_GRID 6250         // N_NODES/16 : one 64-thread wave per 16 nodes

typedef unsigned int  u32;
typedef unsigned short u16;
typedef unsigned char u8;
typedef unsigned long long u64;
typedef __attribute__((ext_vector_type(8))) short bf16x8;
typedef __attribute__((ext_vector_type(4))) float f32x4;

__device__ __forceinline__ float bflo(u32 u){ return __uint_as_float(u << 16); }
__device__ __forceinline__ float bfhi(u32 u){ return __uint_as_float(u & 0xFFFF0000u); }
__device__ __forceinline__ u32 f2b(float f){
  u32 u = __float_as_uint(f);
  return (u + 0x7FFFu + ((u >> 16) & 1u)) >> 16;   // RNE
}
__device__ __forceinline__ u32 pack2(float a, float b){ return f2b(a) | (f2b(b) << 16); }
__device__ __forceinline__ u32 clampN(int s){
  u32 u = (u32)s;
  return (u < (u32)N_NODES) ? u : (u32)(N_NODES - 1);
}

// ---------------- detect (fallback path only) ----------------
__global__ __launch_bounds__(64) void detect(const int* __restrict__ ei,
                                             int* __restrict__ flags){
  int l = threadIdx.x;
  int nzodd = (ei[2 * l + 1] != 0) ? 1 : 0;
  #pragma unroll
  for (int o = 32; o > 0; o >>= 1) nzodd += __shfl_xor(nzodd, o, 64);
  if (l == 0) flags[1] = (nzodd == 0) ? 1 : 0;   // 1 => int64
}

// ---------------- W-frag build (once, into workspace) ----------------
// Fragment-major: fid = ntile*256 + kb*64 + lane; elem j of bf16x8 at dst+fid*8 is
// W[(kb*32+(lane>>4)*8+j)*128 + ntile*16+(lane&15)].

__device__ __forceinline__ void prep_body(const float* __restrict__ W,
                                          u16* __restrict__ dst, int tid){
  #pragma unroll
  for (int i = 0; i < 8; ++i){
    int fid   = tid + i * 256;
    int lane  = fid & 63;
    int kb    = (fid >> 6) & 3;
    int ntile = fid >> 8;
    int n  = ntile * 16 + (lane & 15);
    int k0 = kb * 32 + (lane >> 4) * 8;
    u16 tmp[8];
    #pragma unroll
    for (int j = 0; j < 8; ++j) tmp[j] = (u16)f2b(W[(k0 + j) * 128 + n]);
    *(bf16x8*)(dst + (size_t)fid * 8) = *(const bf16x8*)tmp;
  }
}

__global__ __launch_bounds__(256) void prep_frags(const float* __restrict__ W1,
                                                  const float* __restrict__ W2,
                                                  u16* __restrict__ w1f,
                                                  u16* __restrict__ w2f){
  prep_body(blockIdx.x ? W2 : W1, blockIdx.x ? w2f : w1f, threadIdx.x);
}

// ---------------- GEMM device bodies (16x16x32 bf16 MFMA, bf16 H output) ----------------
// A-frag: m=lane&15, k=(lane>>4)*8+j   B-frag: n=lane&15, k=(lane>>4)*8+j
// D: col=lane&15, row=(lane>>4)*4+r.  B-frags streamed from prebuilt global buffer
// (coalesced 16B/lane, L2-resident) -- no LDS, no barrier.

__device__ __forceinline__ void gemm_tail(const u16* __restrict__ wfrag,
                                          const bf16x8 afrag[4],
                                          int rowbase, int lane,
                                          u16* __restrict__ Hout, int nrows){
  const int m = lane & 15, q = lane >> 4;
  f32x4 acc[8];
  #pragma unroll
  for (int n = 0; n < 8; ++n) acc[n] = (f32x4){0.f, 0.f, 0.f, 0.f};
  #pragma unroll
  for (int n = 0; n < 8; ++n){
    #pragma unroll
    for (int kb = 0; kb < 4; ++kb){
      bf16x8 bfrag = *(const bf16x8*)(wfrag + ((size_t)(n * 4 + kb) * 64 + lane) * 8);
      acc[n] = __builtin_amdgcn_mfma_f32_16x16x32_bf16(afrag[kb], bfrag, acc[n], 0, 0, 0);
    }
  }
  #pragma unroll
  for (int r = 0; r < 4; ++r){
    int orow = rowbase + q * 4 + r;
    if (orow < nrows){
      u16* Or = Hout + (size_t)orow * 128 + m;
      #pragma unroll
      for (int n = 0; n < 8; ++n) Or[n * 16] = (u16)f2b(acc[n][r]);
    }
  }
}

__device__ __forceinline__ void gemm_f32_body(const u16* __restrict__ wfragG,
                                              const float* __restrict__ A,
                                              u16* __restrict__ Hout, int nrows, int bid){
  const int lane = threadIdx.x & 63;
  const int wv   = threadIdx.x >> 6;
  const int rowbase = bid * 64 + wv * 16;
  const int row  = rowbase + (lane & 15);
  const int rowc = (row < nrows) ? row : (nrows - 1);
  const int q    = lane >> 4;
  bf16x8 afrag[4];
  const float* Ar = A + (size_t)rowc * 128;
  #pragma unroll
  for (int kb = 0; kb < 4; ++kb){
    f32x4 p0 = *(const f32x4*)(Ar + kb * 32 + q * 8);
    f32x4 p1 = *(const f32x4*)(Ar + kb * 32 + q * 8 + 4);
    bf16x8 f;
    f[0] = (short)f2b(p0[0]); f[1] = (short)f2b(p0[1]);
    f[2] = (short)f2b(p0[2]); f[3] = (short)f2b(p0[3]);
    f[4] = (short)f2b(p1[0]); f[5] = (short)f2b(p1[1]);
    f[6] = (short)f2b(p1[2]); f[7] = (short)f2b(p1[3]);
    afrag[kb] = f;
  }
  gemm_tail(wfragG, afrag, rowbase, lane, Hout, nrows);
}

// ---------------- binning body: edges -> per-bucket-contiguous packed buffer ----------------
// 256-node buckets: bucket = dst>>8, pk = src | (dst&255)<<17 (25 bits).
// int64-vs-int32 width detected inline (odd i32 words of int64 ids are all 0).

__device__ __forceinline__ void binA_body(u32* smem /*2*NB+1 u32*/,
                                          const int* __restrict__ ei,
                                          u32* __restrict__ binned,
                                          u32* __restrict__ bucket_fill, int bb){
  u32* cnt   = smem;
  u32* gbase = smem + NB;
  u32* flagp = smem + 2 * NB;
  const int tid = threadIdx.x;
  for (int i = tid; i < NB; i += 256) cnt[i] = 0;
  if (tid < 64){
    int nz = (ei[2 * tid + 1] != 0) ? 1 : 0;
    u64 b = __ballot(nz);
    if (tid == 0) *flagp = (b == 0ull) ? 1u : 0u;   // 1 => int64
  }
  __syncthreads();
  const int i64  = (int)*flagp;
  const int base = bb * 4096;
  u32 pk[16], rk[16], bk[16];
  #pragma unroll
  for (int j = 0; j < 16; ++j){
    int e = base + tid + j * 256;
    bk[j] = 0xFFFFFFFFu;
    if (e < N_EDGES){
      int dsti = i64 ? ei[2 * N_EDGES + 2 * e] : ei[N_EDGES + e];
      int srci = i64 ? ei[2 * e]               : ei[e];
      u32 ud = clampN(dsti), us = clampN(srci);
      u32 b = ud >> 8;
      bk[j] = b;
      pk[j] = us | ((ud & 255u) << 17);
      rk[j] = atomicAdd(&cnt[b], 1u);
    }
  }
  __syncthreads();
  for (int i = tid; i < NB; i += 256){
    u32 c = cnt[i];
    gbase[i] = c ? atomicAdd(&bucket_fill[i], c) : 0u;
  }
  __syncthreads();
  #pragma unroll
  for (int j = 0; j < 16; ++j){
    if (bk[j] != 0xFFFFFFFFu){
      u32 idx = gbase[bk[j]] + rk[j];
      if (idx < BKT_CAP) binned[(size_t)bk[j] * BKT_CAP + idx] = pk[j];
    }
  }
}

// ---------------- dispatch 1: binning + W-frag prep ----------------

__global__ __launch_bounds__(256) void bin_prep(const int* __restrict__ ei,
                                                u32* __restrict__ binned,
                                                u32* __restrict__ bucket_fill,
                                                const float* __restrict__ W1,
                                                const float* __restrict__ W2,
                                                u16* __restrict__ w1f,
                                                u16* __restrict__ w2f){
  __shared__ u32 smem[2 * NB + 1];
  if (blockIdx.x < BIN_GRID){
    binA_body(smem, ei, binned, bucket_fill, blockIdx.x);
  } else {
    int pb = blockIdx.x - BIN_GRID;
    prep_body(pb ? W2 : W1, pb ? w2f : w1f, threadIdx.x);
  }
}

// ---------------- fill_sort body: one block per 256-node bucket ----------------

__device__ __forceinline__ void fill_sort_body(u32* smem /*768 u32*/,
                                               const u32* __restrict__ binned,
                                               const u32* __restrict__ bucket_fill,
                                               int* __restrict__ offs,
                                               float* __restrict__ dinv,
                                               int* __restrict__ srclist, int b){
  u32* cnt = smem;
  u32* sc  = smem + 256;
  u32* red = smem + 512;
  const int tid = threadIdx.x;
  cnt[tid] = 0;

  // base = sum over buckets < b of min(fill, CAP)
  u32 v = 0;
  for (int i = tid; i < b; i += 256){
    u32 f = bucket_fill[i];
    v += (f > BKT_CAP) ? BKT_CAP : f;
  }
  red[tid] = v;
  __syncthreads();
  for (int o = 128; o > 0; o >>= 1){
    if (tid < o) red[tid] += red[tid + o];
    __syncthreads();
  }
  const u32 base = red[0];

  u32 n = bucket_fill[b]; if (n > BKT_CAP) n = BKT_CAP;
  const u32* eb = binned + (size_t)b * BKT_CAP;

  // count pass (cnt zeroed before first barrier above)
  for (u32 i = tid; i < n; i += 256)
    atomicAdd(&cnt[eb[i] >> 17], 1u);
  __syncthreads();

  // inclusive Hillis-Steele scan of cnt -> sc
  u32 own = cnt[tid];
  sc[tid] = own;
  __syncthreads();
  for (int o = 1; o < 256; o <<= 1){
    u32 add = (tid >= o) ? sc[tid - o] : 0;
    __syncthreads();
    sc[tid] += add;
    __syncthreads();
  }
  u32 pex = sc[tid] - own;                        // exclusive

  const u32 node = ((u32)b << 8) + tid;
  if (node < (u32)N_NODES){
    offs[node] = (int)(base + pex);
    dinv[node] = rsqrtf((float)own + 1.0f);
  }
  if (b == NB - 1 && tid == 0) offs[N_NODES] = (int)(base + n);

  __syncthreads();
  sc[tid]  = pex;                                 // exclusive base per node
  cnt[tid] = 0;
  __syncthreads();

  // scatter pass
  for (u32 i = tid; i < n; i += 256){
    u32 pk = eb[i];
    u32 d  = pk >> 17;
    u32 r  = atomicAdd(&cnt[d], 1u);
    srclist[base + sc[d] + r] = (int)(pk & 0x1FFFFu);   // value < N (clamped at pack)
  }
}

// ---------------- dispatch 2: fill_sort (blocks 0..NB-1) + gemm1 (rest) ----------------

__global__ __launch_bounds__(256) void fused_fs_gemm(const u32* __restrict__ binned,
                                                     const u32* __restrict__ bucket_fill,
                                                     int* __restrict__ offs,
                                                     float* __restrict__ dinv,
                                                     int* __restrict__ srclist,
                                                     const float* __restrict__ A,
                                                     const u16* __restrict__ w1frag,
                                                     u16* __restrict__ Hout){
  __shared__ u32 smem[768];
  if (blockIdx.x < NB){
    fill_sort_body(smem, binned, bucket_fill, offs, dinv, srclist, blockIdx.x);
  } else {
    gemm_f32_body(w1frag, A, Hout, N_NODES, blockIdx.x - NB);
  }
}

// standalone gemm (fallback path layer 1)
__global__ __launch_bounds__(256) void gemm_f32in(const float* __restrict__ A,
                                                  const u16* __restrict__ wfragG,
                                                  u16* __restrict__ Hout){
  gemm_f32_body(wfragG, A, Hout, N_NODES, blockIdx.x);
}

// ---------------- fallback CSR kernels (used if ws too small) ----------------

__global__ __launch_bounds__(256) void count_deg(const int* __restrict__ ei,
                                                 const int* __restrict__ flags,
                                                 int* __restrict__ deg){
  int e   = blockIdx.x * 256 + threadIdx.x;
  int i64 = flags[1];
  int dst = i64 ? ei[2 * N_EDGES + 2 * e] : ei[N_EDGES + e];
  if ((unsigned)dst < (unsigned)N_NODES) atomicAdd(&deg[dst], 1);
}

__global__ __launch_bounds__(256) void fill_edges(const int* __restrict__ ei,
                                                  const int* __restrict__ flags,
                                                  int* __restrict__ woff,
                                                  int* __restrict__ srclist){
  int e   = blockIdx.x * 256 + threadIdx.x;
  int i64 = flags[1];
  int dst = i64 ? ei[2 * N_EDGES + 2 * e] : ei[N_EDGES + e];
  int src = i64 ? ei[2 * e]               : ei[e];
  if ((unsigned)dst < (unsigned)N_NODES){
    int p = atomicAdd(&woff[dst], 1);
    if ((unsigned)p < (unsigned)N_EDGES) srclist[p] = clampN(src);  // keep < N for gathers
  }
}

__global__ __launch_bounds__(256) void scan1(const int* __restrict__ deg,
                                             int* __restrict__ offs,
                                             int* __restrict__ bsum,
                                             float* __restrict__ dinv){
  __shared__ int sh[256];
  int t = threadIdx.x;
  int i = blockIdx.x * 256 + t;
  int v = (i < N_NODES) ? deg[i] : 0;
  if (i < N_NODES) dinv[i] = rsqrtf((float)v + 1.0f);
  sh[t] = v;
  __syncthreads();
  for (int o = 1; o < 256; o <<= 1){
    int add = (t >= o) ? sh[t - o] : 0;
    __syncthreads();
    sh[t] += add;
    __syncthreads();
  }
  if (i < N_NODES) offs[i] = sh[t] - v;
  if (t == 255)    bsum[blockIdx.x] = sh[255];
}

__global__ __launch_bounds__(512) void scan2(const int* __restrict__ bsum,
                                             int* __restrict__ bofs){
  __shared__ int sh[512];
  int t = threadIdx.x;
  int v = (t < NBLK_N) ? bsum[t] : 0;
  sh[t] = v;
  __syncthreads();
  for (int o = 1; o < 512; o <<= 1){
    int add = (t >= o) ? sh[t - o] : 0;
    __syncthreads();
    sh[t] += add;
    __syncthreads();
  }
  if (t < NBLK_N) bofs[t] = sh[t] - v;
}

__global__ __launch_bounds__(256) void finalize_offs(int* __restrict__ offs,
                                                     const int* __restrict__ bofs,
                                                     int* __restrict__ woff){
  int i = blockIdx.x * 256 + threadIdx.x;
  if (i < N_NODES){
    int o = offs[i] + bofs[blockIdx.x];
    offs[i] = o;
    woff[i] = o;
  }
  if (i == 0) offs[N_NODES] = N_EDGES;
}

// ---------------- gathers ----------------
// srclist entries are guaranteed < N (clamped at binning / fallback fill) -> no per-edge clamp.
// VALIDATED FLOOR (75us @ 3.3TB/s): inner edge loop must stay r10-identical; no
// cross-wave coupling (r11/r12 both regressed).

#define GATHER_EDGE(sv, A0, A1)                         \
  { u32 s_ = (u32)(sv);                                 \
    float w_ = dinv[s_];                                \
    u32 h_ = H[s_ * 64 + lane];                         \
    A0 = fmaf(w_, bflo(h_), A0);                        \
    A1 = fmaf(w_, bfhi(h_), A1); }

#define GATHER_BODY                                     \
  int beg = offs[node], end = offs[node + 1];           \
  if (end > N_EDGES) end = N_EDGES;                     \
  if (beg < 0 || beg > end) beg = end;                  \
  float a0 = 0.f, a1 = 0.f, c0 = 0.f, c1 = 0.f;         \
  int e = beg;                                          \
  for (; e + 8 <= end; e += 8){                         \
    int s0=srcl[e],s1=srcl[e+1],s2=srcl[e+2],s3=srcl[e+3]; \
    int s4=srcl[e+4],s5=srcl[e+5],s6=srcl[e+6],s7=srcl[e+7]; \
    GATHER_EDGE(s0,a0,a1) GATHER_EDGE(s1,c0,c1)         \
    GATHER_EDGE(s2,a0,a1) GATHER_EDGE(s3,c0,c1)         \
    GATHER_EDGE(s4,a0,a1) GATHER_EDGE(s5,c0,c1)         \
    GATHER_EDGE(s6,a0,a1) GATHER_EDGE(s7,c0,c1)         \
  }                                                     \
  for (; e + 4 <= end; e += 4){                         \
    int s0=srcl[e],s1=srcl[e+1],s2=srcl[e+2],s3=srcl[e+3]; \
    GATHER_EDGE(s0,a0,a1) GATHER_EDGE(s1,c0,c1)         \
    GATHER_EDGE(s2,a0,a1) GATHER_EDGE(s3,c0,c1)         \
  }                                                     \
  for (; e < end; ++e){ int s0=srcl[e]; GATHER_EDGE(s0,a0,a1) } \
  a0 += c0;  a1 += c1;                                  \
  float di = dinv[node];                                \
  u32 hs = H[(u32)node * 64 + lane];                    \
  float v0 = fmaf(a0, di, fmaf(bflo(hs), di * di, bb0)); \
  float v1 = fmaf(a1, di, fmaf(bfhi(hs), di * di, bb1));

// fused gather_relu + layer-2 GEMM, BARRIER-FREE: 1 wave per block, 16 nodes per wave
// gathered serially (inner loop r10-identical), relu rows -> wave-private LDS
// [16][68 u32] (row stride 272B: 16B-aligned for b128 A-frag reads; write side
// bank = (4j+lane)%32, 2-way free). Then 8 ntiles x 4 kb MFMA, B-frags streamed
// from w2frag (L2). Per-wave work = sum of 16 degrees (tight), no __syncthreads.

__global__ __launch_bounds__(64) void gather_relu_mm(const int* __restrict__ offs,
                                                     const int* __restrict__ srcl,
                                                     const u32* __restrict__ H,
                                                     const float* __restrict__ dinv,
                                                     const float* __restrict__ bias,
                                                     const u16* __restrict__ w2frag,
                                                     u16* __restrict__ H2){
  __shared__ u32 xs[16 * 68];
  const int lane = threadIdx.x;        // 64-thread block == one wave
  const int m = lane & 15, q = lane >> 4;
  const int nodebase = blockIdx.x * 16;
  if (nodebase >= N_NODES) return;
  const float bb0 = bias[2 * lane], bb1 = bias[2 * lane + 1];

  #pragma unroll 1
  for (int j = 0; j < 16; ++j){
    const int node = nodebase + j;
    GATHER_BODY
    xs[j * 68 + lane] = pack2(fmaxf(v0, 0.f), fmaxf(v1, 0.f));
  }
  // wave-private LDS: compiler inserts lgkmcnt waits; no barrier needed.

  bf16x8 afrag[4];
  #pragma unroll
  for (int kb = 0; kb < 4; ++kb)
    afrag[kb] = *(const bf16x8*)(xs + m * 68 + kb * 16 + q * 4);

  #pragma unroll
  for (int n = 0; n < 8; ++n){
    f32x4 acc = (f32x4){0.f, 0.f, 0.f, 0.f};
    #pragma unroll
    for (int kb = 0; kb < 4; ++kb){
      bf16x8 bfrag = *(const bf16x8*)(w2frag + ((size_t)(n * 4 + kb) * 64 + lane) * 8);
      acc = __builtin_amdgcn_mfma_f32_16x16x32_bf16(afrag[kb], bfrag, acc, 0, 0, 0);
    }
    const int col = n * 16 + m;
    #pragma unroll
    for (int r = 0; r < 4; ++r)
      H2[(size_t)(nodebase + q * 4 + r) * 128 + col] = (u16)f2b(acc[r]);
  }
}

// gather_ln: unchanged r10 structure (LayerNorm needs the full row in one wave).

__global__ __launch_bounds__(256) void gather_ln(const int* __restrict__ offs,
                                                 const int* __restrict__ srcl,
                                                 const u32* __restrict__ H,
                                                 const float* __restrict__ dinv,
                                                 const float* __restrict__ bias,
                                                 const float* __restrict__ gamma,
                                                 const float* __restrict__ beta,
                                                 float* __restrict__ out){
  const int node = blockIdx.x * 4 + (threadIdx.x >> 6);
  const int lane = threadIdx.x & 63;
  const float bb0 = bias[2 * lane], bb1 = bias[2 * lane + 1];
  GATHER_BODY

  float s2 = v0 + v1;
  #pragma unroll
  for (int o = 32; o > 0; o >>= 1) s2 += __shfl_xor(s2, o, 64);
  float mu = s2 * 0.0078125f;
  float d0 = v0 - mu, d1 = v1 - mu;
  float qq = d0 * d0 + d1 * d1;
  #pragma unroll
  for (int o = 32; o > 0; o >>= 1) qq += __shfl_xor(qq, o, 64);
  float rr = rsqrtf(qq * 0.0078125f + 1e-5f);

  float g0 = gamma[2 * lane], g1 = gamma[2 * lane + 1];
  float t0 = beta[2 * lane],  t1 = beta[2 * lane + 1];
  *(float2*)(out + (size_t)node * 128 + 2 * lane) =
      make_float2(fmaf(d0 * rr, g0, t0), fmaf(d1 * rr, g1, t1));
}

// ---------------- launch ----------------

extern "C" void kernel_launch(void* const* d_in, const int* in_sizes, int n_in,
                              void* d_out, int out_size, void* d_ws, size_t ws_size,
                              hipStream_t stream){
  const float* x  = (const float*)d_in[0];
  const int*   ei = (const int*)d_in[1];
  const float* W1 = (const float*)d_in[2];
  const float* b1 = (const float*)d_in[3];
  const float* W2 = (const float*)d_in[4];
  const float* b2 = (const float*)d_in[5];
  const float* gm = (const float*)d_in[6];
  const float* bt = (const float*)d_in[7];

  char* ws = (char*)d_ws;
  size_t off = 0;
  auto carve = [&](size_t bytes) -> void* {
    void* p = ws + off;
    off = (off + bytes + 255) & ~(size_t)255;
    return p;
  };
  int*   flags       = (int*)  carve(64);
  u16*   w1frag      = (u16*)  carve(128 * 128 * 2);         // 32 KB prebuilt B-frags
  u16*   w2frag      = (u16*)  carve(128 * 128 * 2);
  u32*   bucket_fill = (u32*)  carve(NB * 4);
  int*   offs        = (int*)  carve((size_t)(N_NODES + 1) * 4);
  float* dinv        = (float*)carve((size_t)N_NODES * 4);
  int*   srclist     = (int*)  carve((size_t)N_EDGES * 4);
  int*   deg         = (int*)  carve((size_t)N_NODES * 4);   // fallback only (woff)
  int*   bsum        = (int*)  carve(2048);                  // fallback only
  int*   bofs        = (int*)  carve(2048);                  // fallback only

  size_t bin_bytes = (size_t)NB * BKT_CAP * 4;               // 7.4 MB
  u32* binned = (u32*)carve(bin_bytes);
  bool use_binned = (ws_size >= off);
  if (!use_binned) off = (size_t)((char*)binned - ws);       // un-carve

  size_t h_bytes = (size_t)N_NODES * 128 * 2;                // 25.6 MB (bf16)
  u32* H1 = (u32*)d_out;
  u32* H2 = (ws_size >= off + h_bytes) ? (u32*)carve(h_bytes) : (u32*)d_in[0];

  if (use_binned){
    hipMemsetAsync(bucket_fill, 0, NB * 4, stream);
    bin_prep      <<<BIN_GRID + 2, 256, 0, stream>>>(ei, binned, bucket_fill,
                                                     W1, W2, w1frag, w2frag);
    fused_fs_gemm <<<NB + GEMM_GRID, 256, 0, stream>>>(binned, bucket_fill, offs, dinv,
                                                       srclist, x, w1frag, (u16*)H1);
  } else {
    prep_frags    <<<2,             256, 0, stream>>>(W1, W2, w1frag, w2frag);
    hipMemsetAsync(deg, 0, (size_t)N_NODES * 4, stream);
    detect        <<<1,             64,  0, stream>>>(ei, flags);
    count_deg     <<<N_EDGES / 256, 256, 0, stream>>>(ei, flags, deg);
    scan1         <<<NBLK_N,        256, 0, stream>>>(deg, offs, bsum, dinv);
    scan2         <<<1,             512, 0, stream>>>(bsum, bofs);
    finalize_offs <<<NBLK_N,        256, 0, stream>>>(offs, bofs, deg /*woff*/);
    fill_edges    <<<N_EDGES / 256, 256, 0, stream>>>(ei, flags, deg /*woff*/, srclist);
    gemm_f32in    <<<GEMM_GRID,     256, 0, stream>>>(x, w1frag, (u16*)H1);
  }

  gather_relu_mm <<<MM_GRID,     64,  0, stream>>>(offs, srclist, H1, dinv, b1,
                                                   w2frag, (u16*)H2);
  gather_ln      <<<N_NODES / 4, 256, 0, stream>>>(offs, srclist, H2, dinv, b2, gm, bt,
                                                   (float*)d_out);
}

// Round 6
// 300.634 us; speedup vs baseline: 1.0653x; 1.0653x over previous
//
#include <hip/hip_runtime.h>

// GCNEncoder: 2-layer GCN (sym-norm, self-loops) + LayerNorm. N=100000, E=1600000, D=128.
// Round 16. r15 post-mortem: barrier-free fusion CORRECT on traffic (FETCH 199MB,
// WRITE 25MB, MfmaUtil 1.25 as predicted) but 98.8us: 64-thread blocks (1 wave/block)
// hit the per-CU workgroup-slot cap -> Occupancy 31%, BW 2.3TB/s. Fix: same structure,
// 256-thread blocks = 4 INDEPENDENT waves (still no __syncthreads), wave-private LDS
// strips [16][68 u32] (17.4KB/block -> 8 blk/CU = 32 waves/CU). Tail: clamp gathered
// node (garbage A-rows only feed unstored D-rows; 16x16 MFMA row r of D depends only
// on row r of A) and guard H2 stores. Rest of pipeline r14/r15-identical.

#define N_NODES 100000
#define N_EDGES 1600000
#define NBLK_N  391          // ceil(N_NODES/256)
#define NB      391          // buckets = ceil(N/256), 256-node buckets
#define BKT_CAP 4736         // mean 4092 + ~10 sigma, overflow-guarded
#define BIN_GRID 391         // binning blocks, 4096 edges each
#define GEMM_GRID 1563       // ceil(N/64)
#define MM_GRID 1563         // ceil(N/64): 4 waves/block x 16 nodes/wave

typedef unsigned int  u32;
typedef unsigned short u16;
typedef unsigned char u8;
typedef unsigned long long u64;
typedef __attribute__((ext_vector_type(8))) short bf16x8;
typedef __attribute__((ext_vector_type(4))) float f32x4;

__device__ __forceinline__ float bflo(u32 u){ return __uint_as_float(u << 16); }
__device__ __forceinline__ float bfhi(u32 u){ return __uint_as_float(u & 0xFFFF0000u); }
__device__ __forceinline__ u32 f2b(float f){
  u32 u = __float_as_uint(f);
  return (u + 0x7FFFu + ((u >> 16) & 1u)) >> 16;   // RNE
}
__device__ __forceinline__ u32 pack2(float a, float b){ return f2b(a) | (f2b(b) << 16); }
__device__ __forceinline__ u32 clampN(int s){
  u32 u = (u32)s;
  return (u < (u32)N_NODES) ? u : (u32)(N_NODES - 1);
}

// ---------------- detect (fallback path only) ----------------
__global__ __launch_bounds__(64) void detect(const int* __restrict__ ei,
                                             int* __restrict__ flags){
  int l = threadIdx.x;
  int nzodd = (ei[2 * l + 1] != 0) ? 1 : 0;
  #pragma unroll
  for (int o = 32; o > 0; o >>= 1) nzodd += __shfl_xor(nzodd, o, 64);
  if (l == 0) flags[1] = (nzodd == 0) ? 1 : 0;   // 1 => int64
}

// ---------------- W-frag build (once, into workspace) ----------------
// Fragment-major: fid = ntile*256 + kb*64 + lane; elem j of bf16x8 at dst+fid*8 is
// W[(kb*32+(lane>>4)*8+j)*128 + ntile*16+(lane&15)].

__device__ __forceinline__ void prep_body(const float* __restrict__ W,
                                          u16* __restrict__ dst, int tid){
  #pragma unroll
  for (int i = 0; i < 8; ++i){
    int fid   = tid + i * 256;
    int lane  = fid & 63;
    int kb    = (fid >> 6) & 3;
    int ntile = fid >> 8;
    int n  = ntile * 16 + (lane & 15);
    int k0 = kb * 32 + (lane >> 4) * 8;
    u16 tmp[8];
    #pragma unroll
    for (int j = 0; j < 8; ++j) tmp[j] = (u16)f2b(W[(k0 + j) * 128 + n]);
    *(bf16x8*)(dst + (size_t)fid * 8) = *(const bf16x8*)tmp;
  }
}

__global__ __launch_bounds__(256) void prep_frags(const float* __restrict__ W1,
                                                  const float* __restrict__ W2,
                                                  u16* __restrict__ w1f,
                                                  u16* __restrict__ w2f){
  prep_body(blockIdx.x ? W2 : W1, blockIdx.x ? w2f : w1f, threadIdx.x);
}

// ---------------- GEMM device bodies (16x16x32 bf16 MFMA, bf16 H output) ----------------
// A-frag: m=lane&15, k=(lane>>4)*8+j   B-frag: n=lane&15, k=(lane>>4)*8+j
// D: col=lane&15, row=(lane>>4)*4+r.  B-frags streamed from prebuilt global buffer
// (coalesced 16B/lane, L2-resident) -- no LDS, no barrier.

__device__ __forceinline__ void gemm_tail(const u16* __restrict__ wfrag,
                                          const bf16x8 afrag[4],
                                          int rowbase, int lane,
                                          u16* __restrict__ Hout, int nrows){
  const int m = lane & 15, q = lane >> 4;
  f32x4 acc[8];
  #pragma unroll
  for (int n = 0; n < 8; ++n) acc[n] = (f32x4){0.f, 0.f, 0.f, 0.f};
  #pragma unroll
  for (int n = 0; n < 8; ++n){
    #pragma unroll
    for (int kb = 0; kb < 4; ++kb){
      bf16x8 bfrag = *(const bf16x8*)(wfrag + ((size_t)(n * 4 + kb) * 64 + lane) * 8);
      acc[n] = __builtin_amdgcn_mfma_f32_16x16x32_bf16(afrag[kb], bfrag, acc[n], 0, 0, 0);
    }
  }
  #pragma unroll
  for (int r = 0; r < 4; ++r){
    int orow = rowbase + q * 4 + r;
    if (orow < nrows){
      u16* Or = Hout + (size_t)orow * 128 + m;
      #pragma unroll
      for (int n = 0; n < 8; ++n) Or[n * 16] = (u16)f2b(acc[n][r]);
    }
  }
}

__device__ __forceinline__ void gemm_f32_body(const u16* __restrict__ wfragG,
                                              const float* __restrict__ A,
                                              u16* __restrict__ Hout, int nrows, int bid){
  const int lane = threadIdx.x & 63;
  const int wv   = threadIdx.x >> 6;
  const int rowbase = bid * 64 + wv * 16;
  const int row  = rowbase + (lane & 15);
  const int rowc = (row < nrows) ? row : (nrows - 1);
  const int q    = lane >> 4;
  bf16x8 afrag[4];
  const float* Ar = A + (size_t)rowc * 128;
  #pragma unroll
  for (int kb = 0; kb < 4; ++kb){
    f32x4 p0 = *(const f32x4*)(Ar + kb * 32 + q * 8);
    f32x4 p1 = *(const f32x4*)(Ar + kb * 32 + q * 8 + 4);
    bf16x8 f;
    f[0] = (short)f2b(p0[0]); f[1] = (short)f2b(p0[1]);
    f[2] = (short)f2b(p0[2]); f[3] = (short)f2b(p0[3]);
    f[4] = (short)f2b(p1[0]); f[5] = (short)f2b(p1[1]);
    f[6] = (short)f2b(p1[2]); f[7] = (short)f2b(p1[3]);
    afrag[kb] = f;
  }
  gemm_tail(wfragG, afrag, rowbase, lane, Hout, nrows);
}

// ---------------- binning body: edges -> per-bucket-contiguous packed buffer ----------------
// 256-node buckets: bucket = dst>>8, pk = src | (dst&255)<<17 (25 bits).
// int64-vs-int32 width detected inline (odd i32 words of int64 ids are all 0).

__device__ __forceinline__ void binA_body(u32* smem /*2*NB+1 u32*/,
                                          const int* __restrict__ ei,
                                          u32* __restrict__ binned,
                                          u32* __restrict__ bucket_fill, int bb){
  u32* cnt   = smem;
  u32* gbase = smem + NB;
  u32* flagp = smem + 2 * NB;
  const int tid = threadIdx.x;
  for (int i = tid; i < NB; i += 256) cnt[i] = 0;
  if (tid < 64){
    int nz = (ei[2 * tid + 1] != 0) ? 1 : 0;
    u64 b = __ballot(nz);
    if (tid == 0) *flagp = (b == 0ull) ? 1u : 0u;   // 1 => int64
  }
  __syncthreads();
  const int i64  = (int)*flagp;
  const int base = bb * 4096;
  u32 pk[16], rk[16], bk[16];
  #pragma unroll
  for (int j = 0; j < 16; ++j){
    int e = base + tid + j * 256;
    bk[j] = 0xFFFFFFFFu;
    if (e < N_EDGES){
      int dsti = i64 ? ei[2 * N_EDGES + 2 * e] : ei[N_EDGES + e];
      int srci = i64 ? ei[2 * e]               : ei[e];
      u32 ud = clampN(dsti), us = clampN(srci);
      u32 b = ud >> 8;
      bk[j] = b;
      pk[j] = us | ((ud & 255u) << 17);
      rk[j] = atomicAdd(&cnt[b], 1u);
    }
  }
  __syncthreads();
  for (int i = tid; i < NB; i += 256){
    u32 c = cnt[i];
    gbase[i] = c ? atomicAdd(&bucket_fill[i], c) : 0u;
  }
  __syncthreads();
  #pragma unroll
  for (int j = 0; j < 16; ++j){
    if (bk[j] != 0xFFFFFFFFu){
      u32 idx = gbase[bk[j]] + rk[j];
      if (idx < BKT_CAP) binned[(size_t)bk[j] * BKT_CAP + idx] = pk[j];
    }
  }
}

// ---------------- dispatch 1: binning + W-frag prep ----------------

__global__ __launch_bounds__(256) void bin_prep(const int* __restrict__ ei,
                                                u32* __restrict__ binned,
                                                u32* __restrict__ bucket_fill,
                                                const float* __restrict__ W1,
                                                const float* __restrict__ W2,
                                                u16* __restrict__ w1f,
                                                u16* __restrict__ w2f){
  __shared__ u32 smem[2 * NB + 1];
  if (blockIdx.x < BIN_GRID){
    binA_body(smem, ei, binned, bucket_fill, blockIdx.x);
  } else {
    int pb = blockIdx.x - BIN_GRID;
    prep_body(pb ? W2 : W1, pb ? w2f : w1f, threadIdx.x);
  }
}

// ---------------- fill_sort body: one block per 256-node bucket ----------------

__device__ __forceinline__ void fill_sort_body(u32* smem /*768 u32*/,
                                               const u32* __restrict__ binned,
                                               const u32* __restrict__ bucket_fill,
                                               int* __restrict__ offs,
                                               float* __restrict__ dinv,
                                               int* __restrict__ srclist, int b){
  u32* cnt = smem;
  u32* sc  = smem + 256;
  u32* red = smem + 512;
  const int tid = threadIdx.x;
  cnt[tid] = 0;

  // base = sum over buckets < b of min(fill, CAP)
  u32 v = 0;
  for (int i = tid; i < b; i += 256){
    u32 f = bucket_fill[i];
    v += (f > BKT_CAP) ? BKT_CAP : f;
  }
  red[tid] = v;
  __syncthreads();
  for (int o = 128; o > 0; o >>= 1){
    if (tid < o) red[tid] += red[tid + o];
    __syncthreads();
  }
  const u32 base = red[0];

  u32 n = bucket_fill[b]; if (n > BKT_CAP) n = BKT_CAP;
  const u32* eb = binned + (size_t)b * BKT_CAP;

  // count pass (cnt zeroed before first barrier above)
  for (u32 i = tid; i < n; i += 256)
    atomicAdd(&cnt[eb[i] >> 17], 1u);
  __syncthreads();

  // inclusive Hillis-Steele scan of cnt -> sc
  u32 own = cnt[tid];
  sc[tid] = own;
  __syncthreads();
  for (int o = 1; o < 256; o <<= 1){
    u32 add = (tid >= o) ? sc[tid - o] : 0;
    __syncthreads();
    sc[tid] += add;
    __syncthreads();
  }
  u32 pex = sc[tid] - own;                        // exclusive

  const u32 node = ((u32)b << 8) + tid;
  if (node < (u32)N_NODES){
    offs[node] = (int)(base + pex);
    dinv[node] = rsqrtf((float)own + 1.0f);
  }
  if (b == NB - 1 && tid == 0) offs[N_NODES] = (int)(base + n);

  __syncthreads();
  sc[tid]  = pex;                                 // exclusive base per node
  cnt[tid] = 0;
  __syncthreads();

  // scatter pass
  for (u32 i = tid; i < n; i += 256){
    u32 pk = eb[i];
    u32 d  = pk >> 17;
    u32 r  = atomicAdd(&cnt[d], 1u);
    srclist[base + sc[d] + r] = (int)(pk & 0x1FFFFu);   // value < N (clamped at pack)
  }
}

// ---------------- dispatch 2: fill_sort (blocks 0..NB-1) + gemm1 (rest) ----------------

__global__ __launch_bounds__(256) void fused_fs_gemm(const u32* __restrict__ binned,
                                                     const u32* __restrict__ bucket_fill,
                                                     int* __restrict__ offs,
                                                     float* __restrict__ dinv,
                                                     int* __restrict__ srclist,
                                                     const float* __restrict__ A,
                                                     const u16* __restrict__ w1frag,
                                                     u16* __restrict__ Hout){
  __shared__ u32 smem[768];
  if (blockIdx.x < NB){
    fill_sort_body(smem, binned, bucket_fill, offs, dinv, srclist, blockIdx.x);
  } else {
    gemm_f32_body(w1frag, A, Hout, N_NODES, blockIdx.x - NB);
  }
}

// standalone gemm (fallback path layer 1)
__global__ __launch_bounds__(256) void gemm_f32in(const float* __restrict__ A,
                                                  const u16* __restrict__ wfragG,
                                                  u16* __restrict__ Hout){
  gemm_f32_body(wfragG, A, Hout, N_NODES, blockIdx.x);
}

// ---------------- fallback CSR kernels (used if ws too small) ----------------

__global__ __launch_bounds__(256) void count_deg(const int* __restrict__ ei,
                                                 const int* __restrict__ flags,
                                                 int* __restrict__ deg){
  int e   = blockIdx.x * 256 + threadIdx.x;
  int i64 = flags[1];
  int dst = i64 ? ei[2 * N_EDGES + 2 * e] : ei[N_EDGES + e];
  if ((unsigned)dst < (unsigned)N_NODES) atomicAdd(&deg[dst], 1);
}

__global__ __launch_bounds__(256) void fill_edges(const int* __restrict__ ei,
                                                  const int* __restrict__ flags,
                                                  int* __restrict__ woff,
                                                  int* __restrict__ srclist){
  int e   = blockIdx.x * 256 + threadIdx.x;
  int i64 = flags[1];
  int dst = i64 ? ei[2 * N_EDGES + 2 * e] : ei[N_EDGES + e];
  int src = i64 ? ei[2 * e]               : ei[e];
  if ((unsigned)dst < (unsigned)N_NODES){
    int p = atomicAdd(&woff[dst], 1);
    if ((unsigned)p < (unsigned)N_EDGES) srclist[p] = clampN(src);  // keep < N for gathers
  }
}

__global__ __launch_bounds__(256) void scan1(const int* __restrict__ deg,
                                             int* __restrict__ offs,
                                             int* __restrict__ bsum,
                                             float* __restrict__ dinv){
  __shared__ int sh[256];
  int t = threadIdx.x;
  int i = blockIdx.x * 256 + t;
  int v = (i < N_NODES) ? deg[i] : 0;
  if (i < N_NODES) dinv[i] = rsqrtf((float)v + 1.0f);
  sh[t] = v;
  __syncthreads();
  for (int o = 1; o < 256; o <<= 1){
    int add = (t >= o) ? sh[t - o] : 0;
    __syncthreads();
    sh[t] += add;
    __syncthreads();
  }
  if (i < N_NODES) offs[i] = sh[t] - v;
  if (t == 255)    bsum[blockIdx.x] = sh[255];
}

__global__ __launch_bounds__(512) void scan2(const int* __restrict__ bsum,
                                             int* __restrict__ bofs){
  __shared__ int sh[512];
  int t = threadIdx.x;
  int v = (t < NBLK_N) ? bsum[t] : 0;
  sh[t] = v;
  __syncthreads();
  for (int o = 1; o < 512; o <<= 1){
    int add = (t >= o) ? sh[t - o] : 0;
    __syncthreads();
    sh[t] += add;
    __syncthreads();
  }
  if (t < NBLK_N) bofs[t] = sh[t] - v;
}

__global__ __launch_bounds__(256) void finalize_offs(int* __restrict__ offs,
                                                     const int* __restrict__ bofs,
                                                     int* __restrict__ woff){
  int i = blockIdx.x * 256 + threadIdx.x;
  if (i < N_NODES){
    int o = offs[i] + bofs[blockIdx.x];
    offs[i] = o;
    woff[i] = o;
  }
  if (i == 0) offs[N_NODES] = N_EDGES;
}

// ---------------- gathers ----------------
// srclist entries are guaranteed < N (clamped at binning / fallback fill) -> no per-edge clamp.
// VALIDATED FLOOR (75us @ 3.3TB/s): inner edge loop must stay r10-identical; no
// cross-wave coupling (r11/r12 regressed); >=4 waves/block for occupancy (r15).

#define GATHER_EDGE(sv, A0, A1)                         \
  { u32 s_ = (u32)(sv);                                 \
    float w_ = dinv[s_];                                \
    u32 h_ = H[s_ * 64 + lane];                         \
    A0 = fmaf(w_, bflo(h_), A0);                        \
    A1 = fmaf(w_, bfhi(h_), A1); }

#define GATHER_BODY                                     \
  int beg = offs[node], end = offs[node + 1];           \
  if (end > N_EDGES) end = N_EDGES;                     \
  if (beg < 0 || beg > end) beg = end;                  \
  float a0 = 0.f, a1 = 0.f, c0 = 0.f, c1 = 0.f;         \
  int e = beg;                                          \
  for (; e + 8 <= end; e += 8){                         \
    int s0=srcl[e],s1=srcl[e+1],s2=srcl[e+2],s3=srcl[e+3]; \
    int s4=srcl[e+4],s5=srcl[e+5],s6=srcl[e+6],s7=srcl[e+7]; \
    GATHER_EDGE(s0,a0,a1) GATHER_EDGE(s1,c0,c1)         \
    GATHER_EDGE(s2,a0,a1) GATHER_EDGE(s3,c0,c1)         \
    GATHER_EDGE(s4,a0,a1) GATHER_EDGE(s5,c0,c1)         \
    GATHER_EDGE(s6,a0,a1) GATHER_EDGE(s7,c0,c1)         \
  }                                                     \
  for (; e + 4 <= end; e += 4){                         \
    int s0=srcl[e],s1=srcl[e+1],s2=srcl[e+2],s3=srcl[e+3]; \
    GATHER_EDGE(s0,a0,a1) GATHER_EDGE(s1,c0,c1)         \
    GATHER_EDGE(s2,a0,a1) GATHER_EDGE(s3,c0,c1)         \
  }                                                     \
  for (; e < end; ++e){ int s0=srcl[e]; GATHER_EDGE(s0,a0,a1) } \
  a0 += c0;  a1 += c1;                                  \
  float di = dinv[node];                                \
  u32 hs = H[(u32)node * 64 + lane];                    \
  float v0 = fmaf(a0, di, fmaf(bflo(hs), di * di, bb0)); \
  float v1 = fmaf(a1, di, fmaf(bfhi(hs), di * di, bb1));

// fused gather_relu + layer-2 GEMM, barrier-free, 4 waves/block: wave wv owns nodes
// [blockIdx*64 + wv*16, +16) and a private LDS strip [16][68 u32] (stride 272B:
// 16B-aligned b128 A-frag reads). Gather inner loop r10-identical; then 8 ntile x
// 4 kb MFMA with B-frags streamed from w2frag (L2-resident). No __syncthreads.
// Tail: clamp gathered node (garbage rows unstored), guard H2 stores.

__global__ __launch_bounds__(256) void gather_relu_mm(const int* __restrict__ offs,
                                                      const int* __restrict__ srcl,
                                                      const u32* __restrict__ H,
                                                      const float* __restrict__ dinv,
                                                      const float* __restrict__ bias,
                                                      const u16* __restrict__ w2frag,
                                                      u16* __restrict__ H2){
  __shared__ u32 xs[64 * 68];                    // 17.4 KB, 4 wave-private strips
  const int lane = threadIdx.x & 63;
  const int wv   = threadIdx.x >> 6;
  const int m = lane & 15, q = lane >> 4;
  const int nodebase = blockIdx.x * 64 + wv * 16;
  u32* xw = xs + wv * (16 * 68);
  const float bb0 = bias[2 * lane], bb1 = bias[2 * lane + 1];

  #pragma unroll 1
  for (int j = 0; j < 16; ++j){
    int node = nodebase + j;
    if (node >= N_NODES) node = N_NODES - 1;     // tail clamp: row unstored below
    GATHER_BODY
    xw[j * 68 + lane] = pack2(fmaxf(v0, 0.f), fmaxf(v1, 0.f));
  }
  // wave-private LDS: compiler inserts lgkmcnt waits; no barrier needed.

  bf16x8 afrag[4];
  #pragma unroll
  for (int kb = 0; kb < 4; ++kb)
    afrag[kb] = *(const bf16x8*)(xw + m * 68 + kb * 16 + q * 4);

  #pragma unroll
  for (int n = 0; n < 8; ++n){
    f32x4 acc = (f32x4){0.f, 0.f, 0.f, 0.f};
    #pragma unroll
    for (int kb = 0; kb < 4; ++kb){
      bf16x8 bfrag = *(const bf16x8*)(w2frag + ((size_t)(n * 4 + kb) * 64 + lane) * 8);
      acc = __builtin_amdgcn_mfma_f32_16x16x32_bf16(afrag[kb], bfrag, acc, 0, 0, 0);
    }
    const int col = n * 16 + m;
    #pragma unroll
    for (int r = 0; r < 4; ++r){
      const int row = nodebase + q * 4 + r;
      if (row < N_NODES) H2[(size_t)row * 128 + col] = (u16)f2b(acc[r]);
    }
  }
}

// gather_ln: unchanged r10 structure (LayerNorm needs the full row in one wave).

__global__ __launch_bounds__(256) void gather_ln(const int* __restrict__ offs,
                                                 const int* __restrict__ srcl,
                                                 const u32* __restrict__ H,
                                                 const float* __restrict__ dinv,
                                                 const float* __restrict__ bias,
                                                 const float* __restrict__ gamma,
                                                 const float* __restrict__ beta,
                                                 float* __restrict__ out){
  const int node = blockIdx.x * 4 + (threadIdx.x >> 6);
  const int lane = threadIdx.x & 63;
  const float bb0 = bias[2 * lane], bb1 = bias[2 * lane + 1];
  GATHER_BODY

  float s2 = v0 + v1;
  #pragma unroll
  for (int o = 32; o > 0; o >>= 1) s2 += __shfl_xor(s2, o, 64);
  float mu = s2 * 0.0078125f;
  float d0 = v0 - mu, d1 = v1 - mu;
  float qq = d0 * d0 + d1 * d1;
  #pragma unroll
  for (int o = 32; o > 0; o >>= 1) qq += __shfl_xor(qq, o, 64);
  float rr = rsqrtf(qq * 0.0078125f + 1e-5f);

  float g0 = gamma[2 * lane], g1 = gamma[2 * lane + 1];
  float t0 = beta[2 * lane],  t1 = beta[2 * lane + 1];
  *(float2*)(out + (size_t)node * 128 + 2 * lane) =
      make_float2(fmaf(d0 * rr, g0, t0), fmaf(d1 * rr, g1, t1));
}

// ---------------- launch ----------------

extern "C" void kernel_launch(void* const* d_in, const int* in_sizes, int n_in,
                              void* d_out, int out_size, void* d_ws, size_t ws_size,
                              hipStream_t stream){
  const float* x  = (const float*)d_in[0];
  const int*   ei = (const int*)d_in[1];
  const float* W1 = (const float*)d_in[2];
  const float* b1 = (const float*)d_in[3];
  const float* W2 = (const float*)d_in[4];
  const float* b2 = (const float*)d_in[5];
  const float* gm = (const float*)d_in[6];
  const float* bt = (const float*)d_in[7];

  char* ws = (char*)d_ws;
  size_t off = 0;
  auto carve = [&](size_t bytes) -> void* {
    void* p = ws + off;
    off = (off + bytes + 255) & ~(size_t)255;
    return p;
  };
  int*   flags       = (int*)  carve(64);
  u16*   w1frag      = (u16*)  carve(128 * 128 * 2);         // 32 KB prebuilt B-frags
  u16*   w2frag      = (u16*)  carve(128 * 128 * 2);
  u32*   bucket_fill = (u32*)  carve(NB * 4);
  int*   offs        = (int*)  carve((size_t)(N_NODES + 1) * 4);
  float* dinv        = (float*)carve((size_t)N_NODES * 4);
  int*   srclist     = (int*)  carve((size_t)N_EDGES * 4);
  int*   deg         = (int*)  carve((size_t)N_NODES * 4);   // fallback only (woff)
  int*   bsum        = (int*)  carve(2048);                  // fallback only
  int*   bofs        = (int*)  carve(2048);                  // fallback only

  size_t bin_bytes = (size_t)NB * BKT_CAP * 4;               // 7.4 MB
  u32* binned = (u32*)carve(bin_bytes);
  bool use_binned = (ws_size >= off);
  if (!use_binned) off = (size_t)((char*)binned - ws);       // un-carve

  size_t h_bytes = (size_t)N_NODES * 128 * 2;                // 25.6 MB (bf16)
  u32* H1 = (u32*)d_out;
  u32* H2 = (ws_size >= off + h_bytes) ? (u32*)carve(h_bytes) : (u32*)d_in[0];

  if (use_binned){
    hipMemsetAsync(bucket_fill, 0, NB * 4, stream);
    bin_prep      <<<BIN_GRID + 2, 256, 0, stream>>>(ei, binned, bucket_fill,
                                                     W1, W2, w1frag, w2frag);
    fused_fs_gemm <<<NB + GEMM_GRID, 256, 0, stream>>>(binned, bucket_fill, offs, dinv,
                                                       srclist, x, w1frag, (u16*)H1);
  } else {
    prep_frags    <<<2,             256, 0, stream>>>(W1, W2, w1frag, w2frag);
    hipMemsetAsync(deg, 0, (size_t)N_NODES * 4, stream);
    detect        <<<1,             64,  0, stream>>>(ei, flags);
    count_deg     <<<N_EDGES / 256, 256, 0, stream>>>(ei, flags, deg);
    scan1         <<<NBLK_N,        256, 0, stream>>>(deg, offs, bsum, dinv);
    scan2         <<<1,             512, 0, stream>>>(bsum, bofs);
    finalize_offs <<<NBLK_N,        256, 0, stream>>>(offs, bofs, deg /*woff*/);
    fill_edges    <<<N_EDGES / 256, 256, 0, stream>>>(ei, flags, deg /*woff*/, srclist);
    gemm_f32in    <<<GEMM_GRID,     256, 0, stream>>>(x, w1frag, (u16*)H1);
  }

  gather_relu_mm <<<MM_GRID,     256, 0, stream>>>(offs, srclist, H1, dinv, b1,
                                                   w2frag, (u16*)H2);
  gather_ln      <<<N_NODES / 4, 256, 0, stream>>>(offs, srclist, H2, dinv, b2, gm, bt,
                                                   (float*)d_out);
}